// Round 12
// baseline (374.840 us; speedup 1.0000x reference)
//
#include <hip/hip_runtime.h>

// NewNormalizationUnit: SNN-gate priority encoder + shift encoder + exponent
// adjuster + barrel shifter, reduced to integer bit logic.
//
// Input : P [B,8] float32 in {0.0,1.0} (little-endian bits)
// Output (concat flat, float32):
//   p_norm [B,8] @0 | exp_adj [B,5] @B*8 | sticky [B,1] @B*13 |
//   overflow [B,1] @B*14 | shift [B,3] @B*15
//
// Round 4 kernel (3rd submit; infra failures): LINEAR load stream. Round 3
// (nt loads/stores) = 374.6us; kernel portion ~96us vs 69us byte-floor.
// Theory: per-row paired f4 loads at lane-stride 32B touch each 64B line
// twice per wave; with nt (evict-first) the 2nd half-line access may refetch
// from HBM (up to +134MB reads = +21us ~= the observed gap). Fix: thread t
// loads linear f4 slots G+t / G+256+t (each instr covers contiguous 4KB,
// 1 request per line), then one __shfl_xor(1) re-pairs half-rows: even lanes
// own local rows 0..127, odd lanes 128..255. LDS stride-5/3 writes stay
// 2-way (free) under this row distribution. Stores unchanged (LDS-staged,
// nt, packed f4).
//
// Bit semantics (absmax=0 verified, rounds 1-3):
//   m = bitmask(P[r] >= 0.5); k = msb(m|1); nz = m!=0
//   shift = nz ? 7-k : 0 ; p_norm = ((m>>1) << shift) & 0xFF
//   e0=(k&1)|!nz ; e1=nz&!(k&2) ; e2=nz&(2<=k<=5) ; e3=e4=(k<=5)
//   sticky=m&1 ; overflow=m>>7

#define TILE 256

typedef float f32x4 __attribute__((ext_vector_type(4)));

__device__ __forceinline__ f32x4 shfl_xor1(f32x4 v) {
    f32x4 r;
    r.x = __shfl_xor(v.x, 1);
    r.y = __shfl_xor(v.y, 1);
    r.z = __shfl_xor(v.z, 1);
    r.w = __shfl_xor(v.w, 1);
    return r;
}

__global__ __launch_bounds__(256) void snn_norm_kernel(
    const float* __restrict__ P, float* __restrict__ out, unsigned B)
{
    float* __restrict__ p_norm   = out;
    float* __restrict__ exp_adj  = out + (size_t)B * 8;
    float* __restrict__ sticky   = out + (size_t)B * 13;
    float* __restrict__ overflow = out + (size_t)B * 14;
    float* __restrict__ shamt    = out + (size_t)B * 15;

    __shared__ float lds_pn[TILE * 8];   // 8 KiB
    __shared__ float lds_e [TILE * 5];   // 5 KiB
    __shared__ float lds_sh[TILE * 3];   // 3 KiB

    const unsigned tid = threadIdx.x;
    const size_t tileRow = (size_t)blockIdx.x * TILE;
    const bool fullTile = (tileRow + TILE <= B);

    f32x4 lo, hi;        // the 8 bits of this thread's row
    unsigned lr;         // local row index within the tile

    if (fullTile) {
        // ---- linear loads: each instruction covers a contiguous 4KB ----
        const size_t G = (size_t)blockIdx.x * 512;   // f4 slots per tile = 512
        const f32x4 A  = __builtin_nontemporal_load(
            reinterpret_cast<const f32x4*>(P) + G + tid);
        const f32x4 Bv = __builtin_nontemporal_load(
            reinterpret_cast<const f32x4*>(P) + G + 256 + tid);

        // f4 slot F holds row F>>1, half F&1.
        //   even t=2j: A  = row j     half0 ; partner A = row j     half1
        //   odd  t   : Bv = row 128+j half1 ; partner B = row 128+j half0
        const f32x4 A_p = shfl_xor1(A);
        const f32x4 B_p = shfl_xor1(Bv);

        const bool odd = (tid & 1u);
        lr = (odd ? 128u : 0u) + (tid >> 1);
        lo = odd ? B_p : A;
        hi = odd ? Bv  : A_p;
    } else {
        // ragged tail: per-row loads (correct, slower — unused at B%256==0)
        const size_t r = tileRow + tid;
        if (r < B) {
            lo = __builtin_nontemporal_load(
                reinterpret_cast<const f32x4*>(P) + r * 2);
            hi = __builtin_nontemporal_load(
                reinterpret_cast<const f32x4*>(P) + r * 2 + 1);
        } else {
            lo = f32x4{0.f, 0.f, 0.f, 0.f};
            hi = f32x4{0.f, 0.f, 0.f, 0.f};
        }
        lr = tid;
    }

    // ---- per-row bit logic + LDS staging ----
    if (fullTile || tileRow + lr < B) {
        unsigned m = 0;
        m |= (lo.x >= 0.5f) ? 1u   : 0u;
        m |= (lo.y >= 0.5f) ? 2u   : 0u;
        m |= (lo.z >= 0.5f) ? 4u   : 0u;
        m |= (lo.w >= 0.5f) ? 8u   : 0u;
        m |= (hi.x >= 0.5f) ? 16u  : 0u;
        m |= (hi.y >= 0.5f) ? 32u  : 0u;
        m |= (hi.z >= 0.5f) ? 64u  : 0u;
        m |= (hi.w >= 0.5f) ? 128u : 0u;

        const int k = 31 - __clz((int)(m | 1u));
        const bool nz = (m != 0u);

        const unsigned shift = nz ? (7u - (unsigned)k) : 0u;
        const unsigned pn = ((m >> 1) << shift) & 0xFFu;

        const unsigned e0 = (unsigned)(k & 1) | (nz ? 0u : 1u);
        const unsigned e1 = (nz && ((k & 2) == 0)) ? 1u : 0u;
        const unsigned e2 = (nz && (k >= 2) && (k <= 5)) ? 1u : 0u;
        const unsigned e3 = (k <= 5) ? 1u : 0u;

        f32x4 o0, o1;
        o0.x = (float)( pn       & 1u);
        o0.y = (float)((pn >> 1) & 1u);
        o0.z = (float)((pn >> 2) & 1u);
        o0.w = (float)((pn >> 3) & 1u);
        o1.x = (float)((pn >> 4) & 1u);
        o1.y = (float)((pn >> 5) & 1u);
        o1.z = (float)((pn >> 6) & 1u);
        o1.w = (float)((pn >> 7) & 1u);
        reinterpret_cast<f32x4*>(lds_pn)[lr * 2]     = o0;
        reinterpret_cast<f32x4*>(lds_pn)[lr * 2 + 1] = o1;

        // stride-5 dword LDS writes: 2-way per bank under this lr map (free)
        lds_e[lr * 5 + 0] = (float)e0;
        lds_e[lr * 5 + 1] = (float)e1;
        lds_e[lr * 5 + 2] = (float)e2;
        lds_e[lr * 5 + 3] = (float)e3;
        lds_e[lr * 5 + 4] = (float)e3;

        // stride-3: 2-way (free)
        lds_sh[lr * 3 + 0] = (float)( shift       & 1u);
        lds_sh[lr * 3 + 1] = (float)((shift >> 1) & 1u);
        lds_sh[lr * 3 + 2] = (float)((shift >> 2) & 1u);

        // per-wave: two contiguous 128B segments -> same line count as before
        const size_t r = tileRow + lr;
        __builtin_nontemporal_store((float)(m & 1u),  sticky + r);
        __builtin_nontemporal_store((float)(m >> 7),  overflow + r);
    }

    __syncthreads();

    // ---- drain phase: packed float4, lane-contiguous, nontemporal ----
    if (fullTile) {
        f32x4* __restrict__ pnG = reinterpret_cast<f32x4*>(p_norm + tileRow * 8);
        const f32x4* pnL = reinterpret_cast<const f32x4*>(lds_pn);
        #pragma unroll
        for (int i = 0; i < 2; ++i)                    // 512 f4
            __builtin_nontemporal_store(pnL[tid + i * 256], pnG + tid + i * 256);

        f32x4* __restrict__ eG = reinterpret_cast<f32x4*>(exp_adj + tileRow * 5);
        const f32x4* eL = reinterpret_cast<const f32x4*>(lds_e);
        for (int i = tid; i < TILE * 5 / 4; i += 256)  // 320 f4
            __builtin_nontemporal_store(eL[i], eG + i);

        f32x4* __restrict__ sG = reinterpret_cast<f32x4*>(shamt + tileRow * 3);
        const f32x4* sL = reinterpret_cast<const f32x4*>(lds_sh);
        for (int i = tid; i < TILE * 3 / 4; i += 256)  // 192 f4
            __builtin_nontemporal_store(sL[i], sG + i);
    } else {
        // ragged tail: dword-granular drain
        const unsigned rows = (unsigned)(B - tileRow);
        for (unsigned i = tid; i < rows * 8; i += 256)
            p_norm[tileRow * 8 + i] = lds_pn[i];
        for (unsigned i = tid; i < rows * 5; i += 256)
            exp_adj[tileRow * 5 + i] = lds_e[i];
        for (unsigned i = tid; i < rows * 3; i += 256)
            shamt[tileRow * 3 + i] = lds_sh[i];
    }
}

extern "C" void kernel_launch(void* const* d_in, const int* in_sizes, int n_in,
                              void* d_out, int out_size, void* d_ws, size_t ws_size,
                              hipStream_t stream) {
    const float* P = (const float*)d_in[0];
    float* out = (float*)d_out;
    const unsigned B = (unsigned)(in_sizes[0] / 8);

    const int threads = 256;
    const int blocks = (int)((B + TILE - 1) / TILE);   // one 256-row tile per block
    snn_norm_kernel<<<blocks, threads, 0, stream>>>(P, out, B);
}